// Round 1
// baseline (270.839 us; speedup 1.0000x reference)
//
#include <hip/hip_runtime.h>

typedef float f32x4 __attribute__((ext_vector_type(4)));

#define B_  512
#define T_  64
#define N_  30
#define FIN 512
#define D_  256
#define C_  7

// LDS layout (floats):
//   [0, 16384)      realS[32][512]  (rows 30,31 zeroed)  -- union with xwS[30][256]
//   [16384, 17344)  adjS[30][32]    (cols 30,31 zeroed; rows 16B-aligned for float4)
//   [17344, 17472)  scoreS[4][32]
//   [17472, 17504)  sumS[32]
//   [17504, 17511)  logitS[7]
__global__ __launch_bounds__(256, 2)
void digcn_fused(const float* __restrict__ real,
                 const float* __restrict__ gs,
                 const float* __restrict__ W,
                 const float* __restrict__ conv_bias,
                 const float* __restrict__ pool_w,
                 const float* __restrict__ pool_b,
                 const float* __restrict__ head_w,
                 const float* __restrict__ head_b,
                 float* __restrict__ out)
{
    __shared__ __align__(16) float lds[17536];
    float* adjS   = lds + 16384;
    float* scoreS = lds + 17344;
    float* sumS   = lds + 17472;
    float* logitS = lds + 17504;

    const int tid  = threadIdx.x;
    const int b    = blockIdx.x;
    const int w    = tid >> 6;
    const int l    = tid & 63;
    const int c0   = l * 4;      // this lane's 4 output columns
    const int row0 = w * 8;      // this wave's 8 xw rows

    const float* realb = real + (size_t)b * (N_ * FIN);
    const float* gsb   = gs   + (size_t)b * (T_ * N_ * N_);

    // ---- P0: stage real[b] into LDS (rows 0..29), zero rows 30,31 ----
    #pragma unroll
    for (int it = 0; it < 16; ++it) {
        int idx = (it * 256 + tid) * 4;          // float index
        f32x4 v = (f32x4){0.f, 0.f, 0.f, 0.f};
        if (idx < N_ * FIN) v = *(const f32x4*)(realb + idx);
        *(f32x4*)(lds + idx) = v;
    }
    __syncthreads();

    // ---- P1: xw GEMM (registers) with graph_sigs T-mean interleaved ----
    f32x4 acc[8];
    #pragma unroll
    for (int rr = 0; rr < 8; ++rr) acc[rr] = (f32x4){0.f, 0.f, 0.f, 0.f};
    float adjacc[4] = {0.f, 0.f, 0.f, 0.f};

    // prefetch ts=0 slice (4 elems/thread covers the 900 adj entries)
    float pg[4];
    #pragma unroll
    for (int r = 0; r < 4; ++r) {
        int e = tid + r * 256;
        pg[r] = (e < N_ * N_) ? gsb[e] : 0.f;
    }

    for (int ts = 0; ts < T_; ++ts) {
        float ng[4] = {0.f, 0.f, 0.f, 0.f};
        if (ts < T_ - 1) {
            #pragma unroll
            for (int r = 0; r < 4; ++r) {
                int e = tid + r * 256;
                ng[r] = (e < N_ * N_) ? gsb[(ts + 1) * (N_ * N_) + e] : 0.f;
            }
        }
        #pragma unroll
        for (int half = 0; half < 2; ++half) {
            const int f = ts * 8 + half * 4;
            f32x4 wv[4];
            #pragma unroll
            for (int k = 0; k < 4; ++k)
                wv[k] = *(const f32x4*)(W + (f + k) * D_ + c0);   // coalesced, L1/L2-hot
            #pragma unroll
            for (int rr = 0; rr < 8; ++rr) {
                f32x4 rv = *(const f32x4*)(lds + (row0 + rr) * FIN + f);  // wave-uniform b128 broadcast
                #pragma unroll
                for (int k = 0; k < 4; ++k)
                    acc[rr] += wv[k] * rv[k];
            }
        }
        // accumulate previous slice (load->use distance = 1 full iteration)
        #pragma unroll
        for (int r = 0; r < 4; ++r) adjacc[r] += pg[r];
        #pragma unroll
        for (int r = 0; r < 4; ++r) pg[r] = ng[r];
    }
    __syncthreads();   // all realS reads done; safe to overwrite with xw

    // ---- P2: write adj (mean) and xw to LDS ----
    #pragma unroll
    for (int r = 0; r < 4; ++r) {
        int e = tid + r * 256;
        if (e < N_ * N_) {
            int i = e / N_;
            int j = e - i * N_;
            adjS[i * 32 + j] = adjacc[r] * (1.f / (float)T_);
        }
    }
    if (tid < 60) adjS[(tid >> 1) * 32 + 30 + (tid & 1)] = 0.f;  // zero pad cols
    #pragma unroll
    for (int rr = 0; rr < 8; ++rr) {
        int row = row0 + rr;
        if (row < N_) *(f32x4*)(lds + row * D_ + c0) = acc[rr];   // xwS[30][256]
    }
    __syncthreads();

    // ---- P3: agg = adj^T @ xw, ReLU, pool (thread t owns d = t) ----
    float xcol[N_];
    #pragma unroll
    for (int i = 0; i < N_; ++i) xcol[i] = lds[i * D_ + tid];     // 2-way bank alias = free
    const float bias = conv_bias[tid];
    const float pw   = pool_w[tid];

    #pragma unroll
    for (int j0 = 0; j0 < N_; j0 += 4) {
        f32x4 agg = (f32x4){0.f, 0.f, 0.f, 0.f};
        #pragma unroll
        for (int i = 0; i < N_; ++i) {
            f32x4 a4 = *(const f32x4*)(adjS + i * 32 + j0);       // uniform broadcast
            agg += a4 * xcol[i];
        }
        #pragma unroll
        for (int c = 0; c < 4; ++c) {
            float h = agg[c] + bias;
            h = h > 0.f ? h : 0.f;
            float v = h * pw;
            #pragma unroll
            for (int m = 32; m >= 1; m >>= 1) v += __shfl_xor(v, m, 64);
            if (l == 0) scoreS[w * 32 + j0 + c] = v;
        }
    }
    __syncthreads();

    // ---- P4: combine waves, head matmul, softmax ----
    if (tid < N_)
        sumS[tid] = scoreS[tid] + scoreS[32 + tid] + scoreS[64 + tid] + scoreS[96 + tid]
                  + pool_b[0];
    __syncthreads();
    if (tid < C_) {
        float lg = head_b[tid];
        #pragma unroll
        for (int j = 0; j < N_; ++j) lg += sumS[j] * head_w[tid * N_ + j];
        logitS[tid] = lg;
    }
    __syncthreads();
    if (tid < C_) {
        float m = logitS[0];
        #pragma unroll
        for (int c = 1; c < C_; ++c) m = fmaxf(m, logitS[c]);
        float s = 0.f;
        #pragma unroll
        for (int c = 0; c < C_; ++c) s += expf(logitS[c] - m);
        out[b * C_ + tid] = expf(logitS[tid] - m) / s;
    }
}

extern "C" void kernel_launch(void* const* d_in, const int* in_sizes, int n_in,
                              void* d_out, int out_size, void* d_ws, size_t ws_size,
                              hipStream_t stream) {
    const float* real      = (const float*)d_in[0];
    // d_in[1] (imag) is unused by the forward pass
    const float* gs        = (const float*)d_in[2];
    const float* W         = (const float*)d_in[3];
    const float* conv_bias = (const float*)d_in[4];
    const float* pool_w    = (const float*)d_in[5];
    const float* pool_b    = (const float*)d_in[6];
    const float* head_w    = (const float*)d_in[7];
    const float* head_b    = (const float*)d_in[8];
    float* outp            = (float*)d_out;

    digcn_fused<<<dim3(B_), dim3(256), 0, stream>>>(
        real, gs, W, conv_bias, pool_w, pool_b, head_w, head_b, outp);
}